// Round 11
// baseline (221.300 us; speedup 1.0000x reference)
//
#include <hip/hip_runtime.h>
#include <type_traits>

#define D_MODEL 1024
#define NHEADS 16
#define DHEAD 64
#define SEQ 2048
#define BATCH 2
#define MROWS (BATCH*SEQ)   // 4096
#define NQT (SEQ/64)        // 32 q-tiles per (b,h)

typedef unsigned short ushort_t;
using bf16x8 = __attribute__((ext_vector_type(8))) __bf16;
using us4    = __attribute__((ext_vector_type(4))) unsigned short;
using us8    = __attribute__((ext_vector_type(8))) unsigned short;
using f32x4  = __attribute__((ext_vector_type(4))) float;

__device__ __forceinline__ ushort_t f2bf(float f) {
    unsigned int u = __builtin_bit_cast(unsigned int, f);
    u += 0x7FFFu + ((u >> 16) & 1u);
    return (ushort_t)(u >> 16);
}

// async global->LDS, 16B per lane; LDS dest is wave-uniform base + lane*16
__device__ __forceinline__ void gl2lds(const ushort_t* g, ushort_t* l) {
    __builtin_amdgcn_global_load_lds(
        (const __attribute__((address_space(1))) unsigned int*)g,
        (__attribute__((address_space(3))) unsigned int*)l,
        16, 0, 0);
}

// ---------------------------------------------------------------------------
// Convert fp32 inputs -> canonical bf16: x (4M) + Wq/Wk/Wv/Wo (1M each) = 8M.
// ---------------------------------------------------------------------------
__global__ __launch_bounds__(256) void cvt_kernel(
    const float* __restrict__ x,
    const float* __restrict__ wq, const float* __restrict__ wk,
    const float* __restrict__ wv, const float* __restrict__ wo,
    ushort_t* __restrict__ xb,
    ushort_t* __restrict__ wqb, ushort_t* __restrict__ wkb,
    ushort_t* __restrict__ wvb, ushort_t* __restrict__ wob)
{
    const size_t XN = (size_t)MROWS * D_MODEL;          // 4 Mi
    const size_t WN = (size_t)D_MODEL * D_MODEL;        // 1 Mi
    size_t i = ((size_t)blockIdx.x * 256 + threadIdx.x) * 4;
    const float* s; ushort_t* d; size_t off;
    if (i < XN) { s = x; d = xb; off = i; }
    else {
        size_t j = i - XN;
        int w = (int)(j / WN);
        off = j - (size_t)w * WN;
        s = (w == 0) ? wq : (w == 1) ? wk : (w == 2) ? wv : wo;
        d = (w == 0) ? wqb : (w == 1) ? wkb : (w == 2) ? wvb : wob;
    }
    const f32x4 v = *(const f32x4*)(s + off);
    us4 o;
    #pragma unroll
    for (int t = 0; t < 4; ++t) o[t] = f2bf(v[t]);
    *(us4*)(d + off) = o;
}

// ---------------------------------------------------------------------------
// NT GEMM v2 (m97 structure): Y[M,1024] = A @ W^T + bias (+ residual).
// 128x128 tile, 4 waves each 64x64 (4x4 mfma 16x16x32), BK=32,
// global_load_lds width=16 staging.
// ---------------------------------------------------------------------------
template<typename OutT, bool RES>
__global__ __launch_bounds__(256, 3) void gemm_nt(
    const ushort_t* __restrict__ A,
    const ushort_t* __restrict__ W0, const ushort_t* __restrict__ W1, const ushort_t* __restrict__ W2,
    const float* __restrict__ b0, const float* __restrict__ b1, const float* __restrict__ b2,
    const float* __restrict__ res,
    OutT* __restrict__ Y0, OutT* __restrict__ Y1, OutT* __restrict__ Y2)
{
    constexpr int K  = D_MODEL;
    constexpr int BK = 32;
    __shared__ ushort_t As[128 * BK];   // 8 KB, row-major [row][k]
    __shared__ ushort_t Ws[128 * BK];   // 8 KB

    const int z = blockIdx.z;
    const ushort_t* W  = (z == 0) ? W0 : (z == 1) ? W1 : W2;
    const float* bias  = (z == 0) ? b0 : (z == 1) ? b1 : b2;
    OutT* Y            = (z == 0) ? Y0 : (z == 1) ? Y1 : Y2;

    const int i0 = blockIdx.x * 128;
    const int j0 = blockIdx.y * 128;
    const int tid  = threadIdx.x;
    const int lane = tid & 63;
    const int w    = tid >> 6;
    const int wm   = (w >> 1) * 64;
    const int wn   = (w & 1) * 64;
    const int l15  = lane & 15;
    const int quad = lane >> 4;

    const int srow = lane >> 2;
    const int scol = (lane & 3) * 8;
    const int c0 = w * 2, c1 = w * 2 + 1;
    const ushort_t* gA0 = A + (size_t)(i0 + c0 * 16 + srow) * K + scol;
    const ushort_t* gA1 = A + (size_t)(i0 + c1 * 16 + srow) * K + scol;
    const ushort_t* gW0 = W + (size_t)(j0 + c0 * 16 + srow) * K + scol;
    const ushort_t* gW1 = W + (size_t)(j0 + c1 * 16 + srow) * K + scol;
    ushort_t* lA0 = As + c0 * 512;
    ushort_t* lA1 = As + c1 * 512;
    ushort_t* lW0 = Ws + c0 * 512;
    ushort_t* lW1 = Ws + c1 * 512;

    f32x4 acc[4][4] = {};

    for (int k0 = 0; k0 < K; k0 += BK) {
        gl2lds(gA0 + k0, lA0);
        gl2lds(gA1 + k0, lA1);
        gl2lds(gW0 + k0, lW0);
        gl2lds(gW1 + k0, lW1);
        __syncthreads();

        bf16x8 af[4], wf[4];
        #pragma unroll
        for (int m = 0; m < 4; ++m)
            af[m] = *(const bf16x8*)&As[(wm + m * 16 + l15) * BK + quad * 8];
        #pragma unroll
        for (int n = 0; n < 4; ++n)
            wf[n] = *(const bf16x8*)&Ws[(wn + n * 16 + l15) * BK + quad * 8];
        #pragma unroll
        for (int m = 0; m < 4; ++m)
            #pragma unroll
            for (int n = 0; n < 4; ++n)
                acc[m][n] = __builtin_amdgcn_mfma_f32_16x16x32_bf16(af[m], wf[n], acc[m][n], 0, 0, 0);
        __syncthreads();
    }

    #pragma unroll
    for (int n = 0; n < 4; ++n) {
        const int col = j0 + wn + n * 16 + l15;
        const float bv = bias[col];
        #pragma unroll
        for (int m = 0; m < 4; ++m) {
            #pragma unroll
            for (int r = 0; r < 4; ++r) {
                const int row = i0 + wm + m * 16 + quad * 4 + r;
                float v = acc[m][n][r] + bv;
                if constexpr (RES) v += res[(size_t)row * D_MODEL + col];
                if constexpr (std::is_same<OutT, float>::value)
                    Y[(size_t)row * D_MODEL + col] = v;
                else
                    Y[(size_t)row * D_MODEL + col] = f2bf(v);
            }
        }
    }
}

// ---------------------------------------------------------------------------
// Flash attention v8 (causal) = v7 (paired q-tiles, l-via-MFMA, PASSED) +
// SUPERSTEP: two key-tiles per softmax update. S for tiles kt,kt+1 held in
// registers; ONE max-tree + 2 shfls + ONE alpha-rescale per 128 keys.
// ---------------------------------------------------------------------------
#define VP 72

__device__ __forceinline__ void qk_tile(
    const ushort_t* Ktb, const bf16x8& qf0, const bf16x8& qf1,
    int l15, int quad, f32x4* sv)
{
    #pragma unroll
    for (int f = 0; f < 4; ++f) {
        const bf16x8 kf0 = *(const bf16x8*)&Ktb[(f * 16 + l15) * VP + quad * 8];
        const bf16x8 kf1 = *(const bf16x8*)&Ktb[(f * 16 + l15) * VP + 32 + quad * 8];
        f32x4 s = {};
        s = __builtin_amdgcn_mfma_f32_16x16x32_bf16(kf0, qf0, s, 0, 0, 0);
        s = __builtin_amdgcn_mfma_f32_16x16x32_bf16(kf1, qf1, s, 0, 0, 0);
        sv[f] = s;
    }
}

__device__ __forceinline__ void mask_scale(f32x4* sv, int kt, int q0w, int qg, int quad)
{
    if (kt * 64 + 63 <= q0w) {
        #pragma unroll
        for (int f = 0; f < 4; ++f)
            #pragma unroll
            for (int r = 0; r < 4; ++r) sv[f][r] *= 0.125f;
    } else {
        #pragma unroll
        for (int f = 0; f < 4; ++f) {
            #pragma unroll
            for (int r = 0; r < 4; ++r) {
                const int kg = kt * 64 + f * 16 + quad * 4 + r;
                sv[f][r] = (kg <= qg) ? sv[f][r] * 0.125f : -1e30f;
            }
        }
    }
}

__device__ __forceinline__ void pack_p(const f32x4* sv, ushort_t* PwX, int row, int quad)
{
    #pragma unroll
    for (int f = 0; f < 4; ++f) {
        us4 pk;
        #pragma unroll
        for (int r = 0; r < 4; ++r) pk[r] = f2bf(sv[f][r]);
        *(us4*)&PwX[row * VP + f * 16 + quad * 4] = pk;
    }
}

__device__ __forceinline__ void pv_tile(
    const ushort_t* PwX, const ushort_t* Vtb, const bf16x8* onesf,
    int row, int l15, int quad, f32x4 (&o)[4], f32x4& o4)
{
    #pragma unroll
    for (int s = 0; s < 2; ++s) {
        const bf16x8 pf = *(const bf16x8*)&PwX[row * VP + s * 32 + quad * 8];
        #pragma unroll
        for (int t = 0; t < 4; ++t) {
            const bf16x8 vf = *(const bf16x8*)&Vtb[(t * 16 + l15) * VP + s * 32 + quad * 8];
            o[t] = __builtin_amdgcn_mfma_f32_16x16x32_bf16(vf, pf, o[t], 0, 0, 0);
        }
        o4 = __builtin_amdgcn_mfma_f32_16x16x32_bf16(onesf[s], pf, o4, 0, 0, 0);
    }
}

__global__ __launch_bounds__(256, 3) void attn_kernel(
    const ushort_t* __restrict__ Qg, const ushort_t* __restrict__ Kg,
    const ushort_t* __restrict__ Vg, ushort_t* __restrict__ Og)
{
    __shared__ ushort_t Kt[2][64 * VP];   // [key][dim]
    __shared__ ushort_t Vt[2][64 * VP];   // [dim][key]  (V transposed)
    __shared__ ushort_t Pw0[64 * VP];     // P for tile kt   (wave-private rows)
    __shared__ ushort_t Pw1[64 * VP];     // P for tile kt+1
    __shared__ ushort_t OnesR[16 * VP];   // constant 1.0 region for l-MFMA

    const int bh = blockIdx.y;
    const int b = bh >> 4;
    const int h = bh & 15;
    const int p = blockIdx.x;             // 0..15 (q-tile pair index)
    const int tid  = threadIdx.x;
    const int lane = tid & 63;
    const int w    = tid >> 6;
    const int l15  = lane & 15;
    const int quad = lane >> 4;

    const size_t headoff = (size_t)h * DHEAD;
    const ushort_t* Kbase = Kg + (size_t)(b * SEQ) * D_MODEL + headoff;
    const ushort_t* Vbase = Vg + (size_t)(b * SEQ) * D_MODEL + headoff;

    // staging maps (loop-invariant)
    const int krow = tid >> 3;
    const int kb   = tid & 7;
    const int vkey = tid & 63;
    const int dc0  = tid >> 6;
    const int dc1  = dc0 + 4;

    // init ones region (before the first barrier below)
    for (int i = tid; i < 16 * VP; i += 256) OnesR[i] = 0x3F80;  // bf16 1.0

    const int prow = w * 16 + l15;   // this lane's P/O row (its query)

    bf16x8 onesf[2];
    bool onesLoaded = false;

    for (int half = 0; half < 2; ++half) {
        const int qt = half ? p : (NQT - 1 - p);   // heavy tile first
        const int q0 = qt * 64;
        const int qg = q0 + w * 16 + l15;
        const int q0w = q0 + w * 16;
        const int nkt = qt + 1;

        const size_t qrow = (size_t)(b * SEQ + qg) * D_MODEL + headoff;
        const bf16x8 qf0 = *(const bf16x8*)&Qg[qrow + quad * 8];
        const bf16x8 qf1 = *(const bf16x8*)&Qg[qrow + 32 + quad * 8];

        float m_run = -1e30f;
        f32x4 o[4] = {};   // O^T: row d=t*16+quad*4+r, col query=l15
        f32x4 o4 = {};     // l accumulator

        // stage tile 0 -> buf0 (and tile 1 -> buf1 if present)
        {
            us8 k0 = *(const us8*)&Kbase[(size_t)krow * D_MODEL + kb * 8];
            us8 k1 = *(const us8*)&Kbase[(size_t)(32 + krow) * D_MODEL + kb * 8];
            us8 v0 = *(const us8*)&Vbase[(size_t)vkey * D_MODEL + dc0 * 8];
            us8 v1 = *(const us8*)&Vbase[(size_t)vkey * D_MODEL + dc1 * 8];
            *(us8*)&Kt[0][krow * VP + kb * 8]        = k0;
            *(us8*)&Kt[0][(32 + krow) * VP + kb * 8] = k1;
            #pragma unroll
            for (int j = 0; j < 8; ++j) {
                Vt[0][(dc0 * 8 + j) * VP + vkey] = v0[j];
                Vt[0][(dc1 * 8 + j) * VP + vkey] = v1[j];
            }
            if (nkt > 1) {
                const size_t koff = (size_t)64 * D_MODEL;
                k0 = *(const us8*)&Kbase[koff + (size_t)krow * D_MODEL + kb * 8];
                k1 = *(const us8*)&Kbase[koff + (size_t)(32 + krow) * D_MODEL + kb * 8];
                v0 = *(const us8*)&Vbase[koff + (size_t)vkey * D_MODEL + dc0 * 8];
                v1 = *(const us8*)&Vbase[koff + (size_t)vkey * D_MODEL + dc1 * 8];
                *(us8*)&Kt[1][krow * VP + kb * 8]        = k0;
                *(us8*)&Kt[1][(32 + krow) * VP + kb * 8] = k1;
                #pragma unroll
                for (int j = 0; j < 8; ++j) {
                    Vt[1][(dc0 * 8 + j) * VP + vkey] = v0[j];
                    Vt[1][(dc1 * 8 + j) * VP + vkey] = v1[j];
                }
            }
        }
        __syncthreads();

        if (!onesLoaded) {
            onesf[0] = *(const bf16x8*)&OnesR[l15 * VP + quad * 8];
            onesf[1] = *(const bf16x8*)&OnesR[l15 * VP + 32 + quad * 8];
            onesLoaded = true;
        }

        int kt = 0;
        // -------- superstep: two key-tiles per softmax update --------
        while (kt + 1 < nkt) {
            const bool p0 = (kt + 2 < nkt);
            const bool p1 = (kt + 3 < nkt);
            us8 ka0, ka1, va0, va1, kb0_, kb1_, vb0, vb1;
            if (p0) {
                const size_t koff = (size_t)((kt + 2) * 64) * D_MODEL;
                ka0 = *(const us8*)&Kbase[koff + (size_t)krow * D_MODEL + kb * 8];
                ka1 = *(const us8*)&Kbase[koff + (size_t)(32 + krow) * D_MODEL + kb * 8];
                va0 = *(const us8*)&Vbase[koff + (size_t)vkey * D_MODEL + dc0 * 8];
                va1 = *(const us8*)&Vbase[koff + (size_t)vkey * D_MODEL + dc1 * 8];
            }
            if (p1) {
                const size_t koff = (size_t)((kt + 3) * 64) * D_MODEL;
                kb0_ = *(const us8*)&Kbase[koff + (size_t)krow * D_MODEL + kb * 8];
                kb1_ = *(const us8*)&Kbase[koff + (size_t)(32 + krow) * D_MODEL + kb * 8];
                vb0  = *(const us8*)&Vbase[koff + (size_t)vkey * D_MODEL + dc0 * 8];
                vb1  = *(const us8*)&Vbase[koff + (size_t)vkey * D_MODEL + dc1 * 8];
            }

            f32x4 sv0[4], sv1[4];
            qk_tile(Kt[0], qf0, qf1, l15, quad, sv0);
            qk_tile(Kt[1], qf0, qf1, l15, quad, sv1);
            mask_scale(sv0, kt,     q0w, qg, quad);
            mask_scale(sv1, kt + 1, q0w, qg, quad);

            // combined softmax over 32 in-lane values + 2 shfls
            float mx = -1e30f;
            #pragma unroll
            for (int f = 0; f < 4; ++f) {
                mx = fmaxf(mx, fmaxf(fmaxf(sv0[f][0], sv0[f][1]), fmaxf(sv0[f][2], sv0[f][3])));
                mx = fmaxf(mx, fmaxf(fmaxf(sv1[f][0], sv1[f][1]), fmaxf(sv1[f][2], sv1[f][3])));
            }
            mx = fmaxf(mx, __shfl_xor(mx, 16));
            mx = fmaxf(mx, __shfl_xor(mx, 32));
            const float mn = fmaxf(m_run, mx);
            const float al = __expf(m_run - mn);
            m_run = mn;
            #pragma unroll
            for (int f = 0; f < 4; ++f)
                #pragma unroll
                for (int r = 0; r < 4; ++r) {
                    sv0[f][r] = __expf(sv0[f][r] - mn);
                    sv1[f][r] = __expf(sv1[f][r] - mn);
                }
            #pragma unroll
            for (int t = 0; t < 4; ++t)
                #pragma unroll
                for (int r = 0; r < 4; ++r) o[t][r] *= al;
            #pragma unroll
            for (int r = 0; r < 4; ++r) o4[r] *= al;

            pack_p(sv0, Pw0, prow, quad);
            pack_p(sv1, Pw1, prow, quad);
            __asm__ volatile("s_waitcnt lgkmcnt(0)" ::: "memory");  // wave-private P

            pv_tile(Pw0, Vt[0], onesf, prow, l15, quad, o, o4);
            pv_tile(Pw1, Vt[1], onesf, prow, l15, quad, o, o4);

            // all waves done reading both buffers (lgkm only; vm stays in flight)
            __asm__ volatile("s_waitcnt lgkmcnt(0)\n\ts_barrier" ::: "memory");

            if (p0) {
                *(us8*)&Kt[0][krow * VP + kb * 8]        = ka0;
                *(us8*)&Kt[0][(32 + krow) * VP + kb * 8] = ka1;
                #pragma unroll
                for (int j = 0; j < 8; ++j) {
                    Vt[0][(dc0 * 8 + j) * VP + vkey] = va0[j];
                    Vt[0][(dc1 * 8 + j) * VP + vkey] = va1[j];
                }
            }
            if (p1) {
                *(us8*)&Kt[1][krow * VP + kb * 8]        = kb0_;
                *(us8*)&Kt[1][(32 + krow) * VP + kb * 8] = kb1_;
                #pragma unroll
                for (int j = 0; j < 8; ++j) {
                    Vt[1][(dc0 * 8 + j) * VP + vkey] = vb0[j];
                    Vt[1][(dc1 * 8 + j) * VP + vkey] = vb1[j];
                }
            }
            __asm__ volatile("s_waitcnt lgkmcnt(0)\n\ts_barrier" ::: "memory");
            kt += 2;
        }
        // -------- single tail tile (odd nkt), in buf0 --------
        if (kt < nkt) {
            f32x4 sv0[4];
            qk_tile(Kt[0], qf0, qf1, l15, quad, sv0);
            mask_scale(sv0, kt, q0w, qg, quad);
            float mx = -1e30f;
            #pragma unroll
            for (int f = 0; f < 4; ++f)
                mx = fmaxf(mx, fmaxf(fmaxf(sv0[f][0], sv0[f][1]), fmaxf(sv0[f][2], sv0[f][3])));
            mx = fmaxf(mx, __shfl_xor(mx, 16));
            mx = fmaxf(mx, __shfl_xor(mx, 32));
            const float mn = fmaxf(m_run, mx);
            const float al = __expf(m_run - mn);
            m_run = mn;
            #pragma unroll
            for (int f = 0; f < 4; ++f)
                #pragma unroll
                for (int r = 0; r < 4; ++r) sv0[f][r] = __expf(sv0[f][r] - mn);
            #pragma unroll
            for (int t = 0; t < 4; ++t)
                #pragma unroll
                for (int r = 0; r < 4; ++r) o[t][r] *= al;
            #pragma unroll
            for (int r = 0; r < 4; ++r) o4[r] *= al;

            pack_p(sv0, Pw0, prow, quad);
            __asm__ volatile("s_waitcnt lgkmcnt(0)" ::: "memory");
            pv_tile(Pw0, Vt[0], onesf, prow, l15, quad, o, o4);
            __asm__ volatile("s_waitcnt lgkmcnt(0)\n\ts_barrier" ::: "memory");
        }

        const float inv = 1.f / o4[0];   // l for query l15, in-lane
        const size_t orow = (size_t)(b * SEQ + q0 + w * 16 + l15) * D_MODEL + headoff;
        #pragma unroll
        for (int t = 0; t < 4; ++t) {
            us4 pk;
            #pragma unroll
            for (int r = 0; r < 4; ++r) pk[r] = f2bf(o[t][r] * inv);
            *(us4*)&Og[orow + t * 16 + quad * 4] = pk;
        }
    }
}

// ---------------------------------------------------------------------------
// LayerNorm over last dim (1024), one block per row, fp32 in/out (in-place ok).
// ---------------------------------------------------------------------------
__global__ __launch_bounds__(256) void ln_kernel(
    const float* __restrict__ X, const float* __restrict__ g,
    const float* __restrict__ bta, float* __restrict__ out)
{
    __shared__ float r1[4], r2[4];
    const int row = blockIdx.x;
    const int tid = threadIdx.x;
    const float* p = X + (size_t)row * D_MODEL;
    float v[4]; float s1 = 0.f, s2 = 0.f;
    #pragma unroll
    for (int i = 0; i < 4; ++i) { v[i] = p[tid + 256 * i]; s1 += v[i]; s2 += v[i] * v[i]; }
    #pragma unroll
    for (int d = 32; d >= 1; d >>= 1) { s1 += __shfl_xor(s1, d); s2 += __shfl_xor(s2, d); }
    if ((tid & 63) == 0) { r1[tid >> 6] = s1; r2[tid >> 6] = s2; }
    __syncthreads();
    s1 = r1[0] + r1[1] + r1[2] + r1[3];
    s2 = r2[0] + r2[1] + r2[2] + r2[3];
    const float mu  = s1 * (1.f / D_MODEL);
    const float var = s2 * (1.f / D_MODEL) - mu * mu;
    const float rstd = rsqrtf(var + 1e-5f);
    #pragma unroll
    for (int i = 0; i < 4; ++i) {
        const int c = tid + 256 * i;
        out[(size_t)row * D_MODEL + c] = (v[i] - mu) * rstd * g[c] + bta[c];
    }
}

extern "C" void kernel_launch(void* const* d_in, const int* in_sizes, int n_in,
                              void* d_out, int out_size, void* d_ws, size_t ws_size,
                              hipStream_t stream) {
    const float* x     = (const float*)d_in[0];
    const float* Wq    = (const float*)d_in[1];
    const float* bq    = (const float*)d_in[2];
    const float* Wk    = (const float*)d_in[3];
    const float* bk    = (const float*)d_in[4];
    const float* Wv    = (const float*)d_in[5];
    const float* bv    = (const float*)d_in[6];
    const float* Wo    = (const float*)d_in[7];
    const float* bo    = (const float*)d_in[8];
    const float* gamma = (const float*)d_in[9];
    const float* beta  = (const float*)d_in[10];

    const size_t XN = (size_t)MROWS * D_MODEL;      // 4 Mi elements
    const size_t WN = (size_t)D_MODEL * D_MODEL;    // 1 Mi elements
    ushort_t* wsp = (ushort_t*)d_ws;
    ushort_t* xb  = wsp;
    ushort_t* Yq  = wsp + XN;
    ushort_t* Yk  = wsp + 2 * XN;
    ushort_t* Yv  = wsp + 3 * XN;
    ushort_t* Wqb = wsp + 4 * XN;
    ushort_t* Wkb = Wqb + WN;
    ushort_t* Wvb = Wkb + WN;
    ushort_t* Wob = Wvb + WN;
    ushort_t* ctx = xb;                 // overlay: xb dead after QKV gemm
    float*    pre = (float*)d_out;      // fp32 pre-LN lives in d_out; LN in-place

    cvt_kernel<<<dim3(8192), 256, 0, stream>>>(x, Wq, Wk, Wv, Wo, xb, Wqb, Wkb, Wvb, Wob);

    gemm_nt<ushort_t, false><<<dim3(MROWS / 128, D_MODEL / 128, 3), 256, 0, stream>>>(
        xb, Wqb, Wkb, Wvb, bq, bk, bv, nullptr, Yq, Yk, Yv);

    attn_kernel<<<dim3(SEQ / 128, BATCH * NHEADS), 256, 0, stream>>>(Yq, Yk, Yv, ctx);

    gemm_nt<float, true><<<dim3(MROWS / 128, D_MODEL / 128, 1), 256, 0, stream>>>(
        ctx, Wob, Wob, Wob, bo, bo, bo, x, pre, pre, pre);

    ln_kernel<<<dim3(MROWS), 256, 0, stream>>>(pre, gamma, beta, (float*)d_out);
}

// Round 12
// 218.224 us; speedup vs baseline: 1.0141x; 1.0141x over previous
//
#include <hip/hip_runtime.h>
#include <type_traits>

#define D_MODEL 1024
#define NHEADS 16
#define DHEAD 64
#define SEQ 2048
#define BATCH 2
#define MROWS (BATCH*SEQ)   // 4096
#define NQT (SEQ/64)        // 32 q-tiles per (b,h)

typedef unsigned short ushort_t;
using bf16x8 = __attribute__((ext_vector_type(8))) __bf16;
using us4    = __attribute__((ext_vector_type(4))) unsigned short;
using us8    = __attribute__((ext_vector_type(8))) unsigned short;
using f32x4  = __attribute__((ext_vector_type(4))) float;

__device__ __forceinline__ ushort_t f2bf(float f) {
    unsigned int u = __builtin_bit_cast(unsigned int, f);
    u += 0x7FFFu + ((u >> 16) & 1u);
    return (ushort_t)(u >> 16);
}

// async global->LDS, 16B per lane; LDS dest is wave-uniform base + lane*16
__device__ __forceinline__ void gl2lds(const ushort_t* g, ushort_t* l) {
    __builtin_amdgcn_global_load_lds(
        (const __attribute__((address_space(1))) unsigned int*)g,
        (__attribute__((address_space(3))) unsigned int*)l,
        16, 0, 0);
}

// ---------------------------------------------------------------------------
// Convert fp32 inputs -> canonical bf16: x (4M) + Wq/Wk/Wv/Wo (1M each) = 8M.
// ---------------------------------------------------------------------------
__global__ __launch_bounds__(256) void cvt_kernel(
    const float* __restrict__ x,
    const float* __restrict__ wq, const float* __restrict__ wk,
    const float* __restrict__ wv, const float* __restrict__ wo,
    ushort_t* __restrict__ xb,
    ushort_t* __restrict__ wqb, ushort_t* __restrict__ wkb,
    ushort_t* __restrict__ wvb, ushort_t* __restrict__ wob)
{
    const size_t XN = (size_t)MROWS * D_MODEL;          // 4 Mi
    const size_t WN = (size_t)D_MODEL * D_MODEL;        // 1 Mi
    size_t i = ((size_t)blockIdx.x * 256 + threadIdx.x) * 4;
    const float* s; ushort_t* d; size_t off;
    if (i < XN) { s = x; d = xb; off = i; }
    else {
        size_t j = i - XN;
        int w = (int)(j / WN);
        off = j - (size_t)w * WN;
        s = (w == 0) ? wq : (w == 1) ? wk : (w == 2) ? wv : wo;
        d = (w == 0) ? wqb : (w == 1) ? wkb : (w == 2) ? wvb : wob;
    }
    const f32x4 v = *(const f32x4*)(s + off);
    us4 o;
    #pragma unroll
    for (int t = 0; t < 4; ++t) o[t] = f2bf(v[t]);
    *(us4*)(d + off) = o;
}

// ---------------------------------------------------------------------------
// NT GEMM v3: Y[M,1024] = A @ W^T + bias (+ residual).
// 128x128 tile, 4 waves each 64x64. BK=64 via TWO [128][32] panels (keeps
// m97's proven 64B row pitch; halves barrier count: 16 K-iters).
// TRANSPOSED mfma (wf, af) -> lane holds Y[row=l15][cols quad*4..+3]
// -> vectorized epilogue (us4 / f32x4 stores, f32x4 bias+residual loads).
// ---------------------------------------------------------------------------
template<typename OutT, bool RES>
__global__ __launch_bounds__(256, 3) void gemm_nt(
    const ushort_t* __restrict__ A,
    const ushort_t* __restrict__ W0, const ushort_t* __restrict__ W1, const ushort_t* __restrict__ W2,
    const float* __restrict__ b0, const float* __restrict__ b1, const float* __restrict__ b2,
    const float* __restrict__ res,
    OutT* __restrict__ Y0, OutT* __restrict__ Y1, OutT* __restrict__ Y2)
{
    constexpr int K = D_MODEL;
    __shared__ ushort_t As[2][128 * 32];   // panel s: k-cols [s*32, s*32+32)
    __shared__ ushort_t Ws[2][128 * 32];

    const int z = blockIdx.z;
    const ushort_t* W  = (z == 0) ? W0 : (z == 1) ? W1 : W2;
    const float* bias  = (z == 0) ? b0 : (z == 1) ? b1 : b2;
    OutT* Y            = (z == 0) ? Y0 : (z == 1) ? Y1 : Y2;

    const int i0 = blockIdx.x * 128;
    const int j0 = blockIdx.y * 128;
    const int tid  = threadIdx.x;
    const int lane = tid & 63;
    const int w    = tid >> 6;
    const int wm   = (w >> 1) * 64;
    const int wn   = (w & 1) * 64;
    const int l15  = lane & 15;
    const int quad = lane >> 4;

    // staging map: wave w stages chunks {2w,2w+1}; chunk c = rows [c*16,c*16+16)
    const int srow = lane >> 2;       // 0..15
    const int scol = (lane & 3) * 8;  // 0,8,16,24
    const int c0 = w * 2, c1 = w * 2 + 1;
    const ushort_t* gA0 = A + (size_t)(i0 + c0 * 16 + srow) * K + scol;
    const ushort_t* gA1 = A + (size_t)(i0 + c1 * 16 + srow) * K + scol;
    const ushort_t* gW0 = W + (size_t)(j0 + c0 * 16 + srow) * K + scol;
    const ushort_t* gW1 = W + (size_t)(j0 + c1 * 16 + srow) * K + scol;

    f32x4 acc[4][4] = {};   // acc[m][n]: Y rows wm+m*16+l15, cols wn+n*16+quad*4..+3

    for (int k0 = 0; k0 < K; k0 += 64) {
        gl2lds(gA0 + k0,      &As[0][c0 * 512]);
        gl2lds(gA1 + k0,      &As[0][c1 * 512]);
        gl2lds(gA0 + k0 + 32, &As[1][c0 * 512]);
        gl2lds(gA1 + k0 + 32, &As[1][c1 * 512]);
        gl2lds(gW0 + k0,      &Ws[0][c0 * 512]);
        gl2lds(gW1 + k0,      &Ws[0][c1 * 512]);
        gl2lds(gW0 + k0 + 32, &Ws[1][c0 * 512]);
        gl2lds(gW1 + k0 + 32, &Ws[1][c1 * 512]);
        __syncthreads();

        #pragma unroll
        for (int s = 0; s < 2; ++s) {
            bf16x8 af[4], wf[4];
            #pragma unroll
            for (int m = 0; m < 4; ++m)
                af[m] = *(const bf16x8*)&As[s][(wm + m * 16 + l15) * 32 + quad * 8];
            #pragma unroll
            for (int n = 0; n < 4; ++n)
                wf[n] = *(const bf16x8*)&Ws[s][(wn + n * 16 + l15) * 32 + quad * 8];
            #pragma unroll
            for (int m = 0; m < 4; ++m)
                #pragma unroll
                for (int n = 0; n < 4; ++n)
                    acc[m][n] = __builtin_amdgcn_mfma_f32_16x16x32_bf16(wf[n], af[m], acc[m][n], 0, 0, 0);
        }
        __syncthreads();
    }

    #pragma unroll
    for (int n = 0; n < 4; ++n) {
        const int col = j0 + wn + n * 16 + quad * 4;
        const f32x4 bv = *(const f32x4*)&bias[col];
        #pragma unroll
        for (int m = 0; m < 4; ++m) {
            const int row = i0 + wm + m * 16 + l15;
            if constexpr (std::is_same<OutT, float>::value) {
                f32x4 v;
                #pragma unroll
                for (int r = 0; r < 4; ++r) v[r] = acc[m][n][r] + bv[r];
                if constexpr (RES) {
                    const f32x4 rv = *(const f32x4*)&res[(size_t)row * D_MODEL + col];
                    #pragma unroll
                    for (int r = 0; r < 4; ++r) v[r] += rv[r];
                }
                *(f32x4*)&Y[(size_t)row * D_MODEL + col] = v;
            } else {
                us4 pk;
                #pragma unroll
                for (int r = 0; r < 4; ++r) pk[r] = f2bf(acc[m][n][r] + bv[r]);
                *(us4*)&Y[(size_t)row * D_MODEL + col] = pk;
            }
        }
    }
}

// ---------------------------------------------------------------------------
// Flash attention v7 (causal, r10 version — best measured: 64.5 us).
// Paired q-tiles per block (load balance), K+V in LDS double-buffered,
// S^T = K Q^T (softmax in-lane), O^T = V^T P^T, l via ones-MFMA.
// ---------------------------------------------------------------------------
#define VP 72

__global__ __launch_bounds__(256, 3) void attn_kernel(
    const ushort_t* __restrict__ Qg, const ushort_t* __restrict__ Kg,
    const ushort_t* __restrict__ Vg, ushort_t* __restrict__ Og)
{
    __shared__ ushort_t Kt[2][64 * VP];   // [key][dim]
    __shared__ ushort_t Vt[2][64 * VP];   // [dim][key]  (V transposed)
    __shared__ ushort_t Pw[64 * VP];      // [query][key] (wave-private rows)
    __shared__ ushort_t OnesR[16 * VP];   // constant 1.0 region for l-MFMA

    const int bh = blockIdx.y;
    const int b = bh >> 4;
    const int h = bh & 15;
    const int p = blockIdx.x;             // 0..15 (q-tile pair index)
    const int tid  = threadIdx.x;
    const int lane = tid & 63;
    const int w    = tid >> 6;
    const int l15  = lane & 15;
    const int quad = lane >> 4;

    const size_t headoff = (size_t)h * DHEAD;
    const ushort_t* Kbase = Kg + (size_t)(b * SEQ) * D_MODEL + headoff;
    const ushort_t* Vbase = Vg + (size_t)(b * SEQ) * D_MODEL + headoff;

    const int krow = tid >> 3;
    const int kb   = tid & 7;
    const int vkey = tid & 63;
    const int dc0  = tid >> 6;
    const int dc1  = dc0 + 4;

    for (int i = tid; i < 16 * VP; i += 256) OnesR[i] = 0x3F80;  // bf16 1.0

    bf16x8 onesf[2];
    bool onesLoaded = false;

    for (int half = 0; half < 2; ++half) {
        const int qt = half ? p : (NQT - 1 - p);   // heavy tile first
        const int q0 = qt * 64;
        const int qg = q0 + w * 16 + l15;
        const int nkt = qt + 1;

        const size_t qrow = (size_t)(b * SEQ + qg) * D_MODEL + headoff;
        const bf16x8 qf0 = *(const bf16x8*)&Qg[qrow + quad * 8];
        const bf16x8 qf1 = *(const bf16x8*)&Qg[qrow + 32 + quad * 8];

        float m_run = -1e30f;
        f32x4 o[4] = {};
        f32x4 o4 = {};

        us8 kp0, kp1, vp0, vp1;
        kp0 = *(const us8*)&Kbase[(size_t)krow * D_MODEL + kb * 8];
        kp1 = *(const us8*)&Kbase[(size_t)(32 + krow) * D_MODEL + kb * 8];
        vp0 = *(const us8*)&Vbase[(size_t)vkey * D_MODEL + dc0 * 8];
        vp1 = *(const us8*)&Vbase[(size_t)vkey * D_MODEL + dc1 * 8];
        *(us8*)&Kt[0][krow * VP + kb * 8]        = kp0;
        *(us8*)&Kt[0][(32 + krow) * VP + kb * 8] = kp1;
        #pragma unroll
        for (int j = 0; j < 8; ++j) {
            Vt[0][(dc0 * 8 + j) * VP + vkey] = vp0[j];
            Vt[0][(dc1 * 8 + j) * VP + vkey] = vp1[j];
        }
        __syncthreads();

        if (!onesLoaded) {
            onesf[0] = *(const bf16x8*)&OnesR[l15 * VP + quad * 8];
            onesf[1] = *(const bf16x8*)&OnesR[l15 * VP + 32 + quad * 8];
            onesLoaded = true;
        }

        for (int kt = 0; kt < nkt; ++kt) {
            const int cur = kt & 1;
            const int nxt = cur ^ 1;
            const bool pre = (kt + 1 < nkt);
            if (pre) {
                const size_t koff = (size_t)((kt + 1) * 64) * D_MODEL;
                kp0 = *(const us8*)&Kbase[koff + (size_t)krow * D_MODEL + kb * 8];
                kp1 = *(const us8*)&Kbase[koff + (size_t)(32 + krow) * D_MODEL + kb * 8];
                vp0 = *(const us8*)&Vbase[koff + (size_t)vkey * D_MODEL + dc0 * 8];
                vp1 = *(const us8*)&Vbase[koff + (size_t)vkey * D_MODEL + dc1 * 8];
            }

            f32x4 sv[4];
            #pragma unroll
            for (int f = 0; f < 4; ++f) {
                const bf16x8 kf0 = *(const bf16x8*)&Kt[cur][(f * 16 + l15) * VP + quad * 8];
                const bf16x8 kf1 = *(const bf16x8*)&Kt[cur][(f * 16 + l15) * VP + 32 + quad * 8];
                f32x4 s = {};
                s = __builtin_amdgcn_mfma_f32_16x16x32_bf16(kf0, qf0, s, 0, 0, 0);
                s = __builtin_amdgcn_mfma_f32_16x16x32_bf16(kf1, qf1, s, 0, 0, 0);
                sv[f] = s;
            }

            if (kt * 64 + 63 <= q0 + w * 16) {
                #pragma unroll
                for (int f = 0; f < 4; ++f)
                    #pragma unroll
                    for (int r = 0; r < 4; ++r) sv[f][r] *= 0.125f;
            } else {
                #pragma unroll
                for (int f = 0; f < 4; ++f) {
                    #pragma unroll
                    for (int r = 0; r < 4; ++r) {
                        const int kg = kt * 64 + f * 16 + quad * 4 + r;
                        sv[f][r] = (kg <= qg) ? sv[f][r] * 0.125f : -1e30f;
                    }
                }
            }

            float mf[4];
            #pragma unroll
            for (int f = 0; f < 4; ++f)
                mf[f] = fmaxf(fmaxf(sv[f][0], sv[f][1]), fmaxf(sv[f][2], sv[f][3]));
            float mx = fmaxf(fmaxf(mf[0], mf[1]), fmaxf(mf[2], mf[3]));
            mx = fmaxf(mx, __shfl_xor(mx, 16));
            mx = fmaxf(mx, __shfl_xor(mx, 32));
            const float mn = fmaxf(m_run, mx);
            const float al = __expf(m_run - mn);
            m_run = mn;
            #pragma unroll
            for (int f = 0; f < 4; ++f)
                #pragma unroll
                for (int r = 0; r < 4; ++r) sv[f][r] = __expf(sv[f][r] - mn);

            #pragma unroll
            for (int t = 0; t < 4; ++t)
                #pragma unroll
                for (int r = 0; r < 4; ++r) o[t][r] *= al;
            #pragma unroll
            for (int r = 0; r < 4; ++r) o4[r] *= al;

            #pragma unroll
            for (int f = 0; f < 4; ++f) {
                us4 pk;
                #pragma unroll
                for (int r = 0; r < 4; ++r) pk[r] = f2bf(sv[f][r]);
                *(us4*)&Pw[(w * 16 + l15) * VP + f * 16 + quad * 4] = pk;
            }
            __asm__ volatile("s_waitcnt lgkmcnt(0)" ::: "memory");

            #pragma unroll
            for (int s = 0; s < 2; ++s) {
                const bf16x8 pf = *(const bf16x8*)&Pw[(w * 16 + l15) * VP + s * 32 + quad * 8];
                #pragma unroll
                for (int t = 0; t < 4; ++t) {
                    const bf16x8 vf = *(const bf16x8*)&Vt[cur][(t * 16 + l15) * VP + s * 32 + quad * 8];
                    o[t] = __builtin_amdgcn_mfma_f32_16x16x32_bf16(vf, pf, o[t], 0, 0, 0);
                }
                o4 = __builtin_amdgcn_mfma_f32_16x16x32_bf16(onesf[s], pf, o4, 0, 0, 0);
            }

            if (pre) {
                *(us8*)&Kt[nxt][krow * VP + kb * 8]        = kp0;
                *(us8*)&Kt[nxt][(32 + krow) * VP + kb * 8] = kp1;
                #pragma unroll
                for (int j = 0; j < 8; ++j) {
                    Vt[nxt][(dc0 * 8 + j) * VP + vkey] = vp0[j];
                    Vt[nxt][(dc1 * 8 + j) * VP + vkey] = vp1[j];
                }
            }
            __asm__ volatile("s_waitcnt lgkmcnt(0)\n\ts_barrier" ::: "memory");
        }

        const float inv = 1.f / o4[0];
        const size_t orow = (size_t)(b * SEQ + q0 + w * 16 + l15) * D_MODEL + headoff;
        #pragma unroll
        for (int t = 0; t < 4; ++t) {
            us4 pk;
            #pragma unroll
            for (int r = 0; r < 4; ++r) pk[r] = f2bf(o[t][r] * inv);
            *(us4*)&Og[orow + t * 16 + quad * 4] = pk;
        }
    }
}

// ---------------------------------------------------------------------------
// LayerNorm over last dim (1024), one block per row, fp32 in/out (in-place ok).
// ---------------------------------------------------------------------------
__global__ __launch_bounds__(256) void ln_kernel(
    const float* __restrict__ X, const float* __restrict__ g,
    const float* __restrict__ bta, float* __restrict__ out)
{
    __shared__ float r1[4], r2[4];
    const int row = blockIdx.x;
    const int tid = threadIdx.x;
    const float* p = X + (size_t)row * D_MODEL;
    float v[4]; float s1 = 0.f, s2 = 0.f;
    #pragma unroll
    for (int i = 0; i < 4; ++i) { v[i] = p[tid + 256 * i]; s1 += v[i]; s2 += v[i] * v[i]; }
    #pragma unroll
    for (int d = 32; d >= 1; d >>= 1) { s1 += __shfl_xor(s1, d); s2 += __shfl_xor(s2, d); }
    if ((tid & 63) == 0) { r1[tid >> 6] = s1; r2[tid >> 6] = s2; }
    __syncthreads();
    s1 = r1[0] + r1[1] + r1[2] + r1[3];
    s2 = r2[0] + r2[1] + r2[2] + r2[3];
    const float mu  = s1 * (1.f / D_MODEL);
    const float var = s2 * (1.f / D_MODEL) - mu * mu;
    const float rstd = rsqrtf(var + 1e-5f);
    #pragma unroll
    for (int i = 0; i < 4; ++i) {
        const int c = tid + 256 * i;
        out[(size_t)row * D_MODEL + c] = (v[i] - mu) * rstd * g[c] + bta[c];
    }
}

extern "C" void kernel_launch(void* const* d_in, const int* in_sizes, int n_in,
                              void* d_out, int out_size, void* d_ws, size_t ws_size,
                              hipStream_t stream) {
    const float* x     = (const float*)d_in[0];
    const float* Wq    = (const float*)d_in[1];
    const float* bq    = (const float*)d_in[2];
    const float* Wk    = (const float*)d_in[3];
    const float* bk    = (const float*)d_in[4];
    const float* Wv    = (const float*)d_in[5];
    const float* bv    = (const float*)d_in[6];
    const float* Wo    = (const float*)d_in[7];
    const float* bo    = (const float*)d_in[8];
    const float* gamma = (const float*)d_in[9];
    const float* beta  = (const float*)d_in[10];

    const size_t XN = (size_t)MROWS * D_MODEL;      // 4 Mi elements
    const size_t WN = (size_t)D_MODEL * D_MODEL;    // 1 Mi elements
    ushort_t* wsp = (ushort_t*)d_ws;
    ushort_t* xb  = wsp;
    ushort_t* Yq  = wsp + XN;
    ushort_t* Yk  = wsp + 2 * XN;
    ushort_t* Yv  = wsp + 3 * XN;
    ushort_t* Wqb = wsp + 4 * XN;
    ushort_t* Wkb = Wqb + WN;
    ushort_t* Wvb = Wkb + WN;
    ushort_t* Wob = Wvb + WN;
    ushort_t* ctx = xb;                 // overlay: xb dead after QKV gemm
    float*    pre = (float*)d_out;      // fp32 pre-LN lives in d_out; LN in-place

    cvt_kernel<<<dim3(8192), 256, 0, stream>>>(x, Wq, Wk, Wv, Wo, xb, Wqb, Wkb, Wvb, Wob);

    gemm_nt<ushort_t, false><<<dim3(MROWS / 128, D_MODEL / 128, 3), 256, 0, stream>>>(
        xb, Wqb, Wkb, Wvb, bq, bk, bv, nullptr, Yq, Yk, Yv);

    attn_kernel<<<dim3(SEQ / 128, BATCH * NHEADS), 256, 0, stream>>>(Yq, Yk, Yv, ctx);

    gemm_nt<float, true><<<dim3(MROWS / 128, D_MODEL / 128, 1), 256, 0, stream>>>(
        ctx, Wob, Wob, Wob, bo, bo, bo, x, pre, pre, pre);

    ln_kernel<<<dim3(MROWS), 256, 0, stream>>>(pre, gamma, beta, (float*)d_out);
}